// Round 5
// baseline (425.465 us; speedup 1.0000x reference)
//
#include <hip/hip_runtime.h>
#include <math.h>

#define Cc 256
#define NH 8
#define HD 32
#define Tt 256
#define MH 256
#define TBL 961  // 31*31 distinct relative offsets

typedef _Float16 f16;
typedef f16 f16x8 __attribute__((ext_vector_type(8)));
typedef float f32x4 __attribute__((ext_vector_type(4)));

// stride-32 f16 rows, 16B-chunk XOR swizzle, key=(row>>2)&3.
__device__ __forceinline__ f16x8 ld8(const f16* base, int row, int kc) {
  return *(const f16x8*)&base[row * 32 + ((kc ^ ((row >> 2) & 3)) << 3)];
}
__device__ __forceinline__ void st8(f16* base, int row, int kc, f16x8 v) {
  *(f16x8*)&base[row * 32 + ((kc ^ ((row >> 2) & 3)) << 3)] = v;
}
__device__ __forceinline__ int sidx(int row, int col) {
  return row * 32 + (((col >> 3) ^ ((row >> 2) & 3)) << 3) + (col & 7);
}
// Vt: [d=32][t=256] stride 256, full 3-bit XOR: chunk ^= (d&7).
__device__ __forceinline__ int vsidx(int d, int t) {
  return d * 256 + (((t >> 3) ^ (d & 7)) << 3) + (t & 7);
}
__device__ __forceinline__ f16x8 vld8(const f16* base, int d, int tch) {
  return *(const f16x8*)&base[d * 256 + ((tch ^ (d & 7)) << 3)];
}

// ---------------------------------------------------------------------------
// Kernel 1: prep.  Blocks 0..7: bias-MLP table for one head each (parallel).
// Blocks 8..39: convert w_proj fp32 -> fp16 (row-major [c][k]).
// ---------------------------------------------------------------------------
__global__ __launch_bounds__(256) void prep_kernel(
    const float* __restrict__ mw1, const float* __restrict__ mb1,
    const float* __restrict__ mw2, const float* __restrict__ mb2,
    const float* __restrict__ w_proj, float* __restrict__ table,
    float* __restrict__ tablemax, f16* __restrict__ wpf) {
  int blk = blockIdx.x, tid = threadIdx.x;
  if (blk >= NH) {  // W conversion: 32 blocks x 256 thr x 8 elems = 65536
    int base = (blk - NH) * 2048 + tid * 8;
    f16x8 v;
#pragma unroll
    for (int u = 0; u < 8; u++) v[u] = (f16)w_proj[base + u];
    *(f16x8*)&wpf[base] = v;
    return;
  }
  __shared__ float s_w1a[MH], s_w1b[MH], s_b1[MH], s_w2[MH];
  __shared__ float red[256];
  for (int i = tid; i < MH; i += 256) {
    s_w1a[i] = mw1[2 * i];
    s_w1b[i] = mw1[2 * i + 1];
    s_b1[i] = mb1[i];
    s_w2[i] = mw2[blk * MH + i];
  }
  __syncthreads();
  float lmax = -1e30f;
  float b2 = mb2[blk];
  for (int idx = tid; idx < TBL; idx += 256) {
    float fdi = (float)(idx / 31 - 15);
    float fdj = (float)(idx % 31 - 15);
    float d0 = (fdi > 0.f ? 1.f : (fdi < 0.f ? -1.f : 0.f)) * log1pf(fabsf(fdi));
    float d1 = (fdj > 0.f ? 1.f : (fdj < 0.f ? -1.f : 0.f)) * log1pf(fabsf(fdj));
    float o = b2;
    for (int m = 0; m < MH; m++) {
      float hid = fmaxf(fmaf(d0, s_w1a[m], fmaf(d1, s_w1b[m], s_b1[m])), 0.f);
      o = fmaf(hid, s_w2[m], o);
    }
    table[blk * TBL + idx] = o;
    lmax = fmaxf(lmax, o);
  }
  red[tid] = lmax;
  __syncthreads();
  for (int s = 128; s > 0; s >>= 1) {
    if (tid < s) red[tid] = fmaxf(red[tid], red[tid + s]);
    __syncthreads();
  }
  if (tid == 0) tablemax[blk] = red[0];
}

// ---------------------------------------------------------------------------
// Kernel 2: fully-MFMA fused QKV + cosine-sim attention.  Block = (b,h),
// 512 threads = 8 waves.  LDS 53120 B -> 3 blocks/CU (6 waves/SIMD).
// Region map:  [0]  0..16K   Qa      (phase1: Xa, phase2: per-wave P)
//              [1] 16..32K   Ka      (phase1: Wa in first 6K)
//              [2] 32..48K   Vt (stride 256, full XOR)
//              [3] 48..51.9K tb2 (31x32 f32, log2-domain pre-shifted bias)
// ---------------------------------------------------------------------------
__global__ __launch_bounds__(512, 6) void fused_attn(
    const float* __restrict__ x, const float* __restrict__ w_qkv,
    const float* __restrict__ b_qkv, const float* __restrict__ table,
    const float* __restrict__ tablemax, const float* __restrict__ tau,
    f16* __restrict__ attnH) {
  __shared__ __align__(16) char smem[53120];
  f16* Qa = (f16*)smem;                  // 16384 B
  f16* Ka = (f16*)(smem + 16384);        // 16384 B
  f16* Vt = (f16*)(smem + 32768);        // 16384 B
  float* tb2 = (float*)(smem + 49152);   // 3968 B
  f16* Xa = (f16*)smem;                  // phase-1 alias of Qa region
  f16* Wa = (f16*)(smem + 16384);        // phase-1 alias of Ka region (6 KB)

  int tid = threadIdx.x;
  int bh = blockIdx.x, b = bh >> 3, h = bh & 7;
  int wv = tid >> 6, ln = tid & 63, lq = ln >> 4, lm = ln & 15;

  const float LOG2E = 1.4426950408889634f;
  float rtau = 1.0f / fmaxf(tau[h], 0.01f);
  float tmaxh = tablemax[h];

  // tb2 init (dedicated region, no alias -> do it up front)
  for (int i = tid; i < TBL; i += 512) {
    int di_ = i / 31, dj_ = i % 31;
    tb2[di_ * 32 + dj_] = (table[h * TBL + i] - tmaxh - rtau * 1.0001f) * LOG2E;
  }

  // per-lane qkv bias for the 6 n-tiles (n = nt*16 + lm)
  float bj[6];
#pragma unroll
  for (int nt = 0; nt < 6; nt++) {
    int n = nt * 16 + lm;
    int row = ((n >> 5) << 8) + (h << 5) + (n & 31);
    bj[nt] = b_qkv[row];
  }

  // ---- Phase 1: QKV GEMM, M=256 N=96 K=256, MFMA 16x16x32_f16
  f32x4 acc[2][6] = {};
  for (int c0 = 0; c0 < Cc; c0 += 32) {
    {  // stage Xa[t][c'] fp16 (transpose of x[b][c][t]); coalesced reads
      int t = tid & 255, cg = tid >> 8;
      f16x8 v0, v1;
#pragma unroll
      for (int cc = 0; cc < 8; cc++)
        v0[cc] = (f16)x[(size_t)b * 65536 + (size_t)(c0 + cg * 16 + cc) * 256 + t];
#pragma unroll
      for (int cc = 0; cc < 8; cc++)
        v1[cc] = (f16)x[(size_t)b * 65536 + (size_t)(c0 + cg * 16 + 8 + cc) * 256 + t];
      st8(Xa, t, cg * 2 + 0, v0);
      st8(Xa, t, cg * 2 + 1, v1);
    }
    if (tid < 384) {  // stage Wa[n][c'] fp16
      int n = tid >> 2, ck = tid & 3;
      int row = ((n >> 5) << 8) + (h << 5) + (n & 31);
      const float* wp = w_qkv + (size_t)row * Cc + c0 + ck * 8;
      f16x8 v;
#pragma unroll
      for (int u = 0; u < 8; u++) v[u] = (f16)wp[u];
      st8(Wa, n, ck, v);
    }
    __syncthreads();
    f16x8 af[2], bf[6];
#pragma unroll
    for (int e = 0; e < 2; e++) af[e] = ld8(Xa, wv * 32 + e * 16 + lm, lq);
#pragma unroll
    for (int nt = 0; nt < 6; nt++) bf[nt] = ld8(Wa, nt * 16 + lm, lq);
#pragma unroll
    for (int e = 0; e < 2; e++)
#pragma unroll
      for (int nt = 0; nt < 6; nt++)
        acc[e][nt] = __builtin_amdgcn_mfma_f32_16x16x32_f16(af[e], bf[nt],
                                                            acc[e][nt], 0, 0, 0);
    __syncthreads();
  }

  // epilogue: + bias, scatter to Qa/Ka (t-major) and Vt (d-major)
#pragma unroll
  for (int e = 0; e < 2; e++) {
#pragma unroll
    for (int nt = 0; nt < 6; nt++) {
      int d = (nt & 1) * 16 + lm;
#pragma unroll
      for (int r = 0; r < 4; r++) {
        int t = wv * 32 + e * 16 + lq * 4 + r;
        f16 v = (f16)(acc[e][nt][r] + bj[nt]);
        if (nt < 2)      Qa[sidx(t, d)] = v;
        else if (nt < 4) Ka[sidx(t, d)] = v;
        else             Vt[vsidx(d, t)] = v;
      }
    }
  }
  __syncthreads();

  // normalize Q,K rows in place (chunk order irrelevant for the sum)
  if (tid < 256) {
    int t = tid;
    float s = 0.f;
    f16x8 v[4];
#pragma unroll
    for (int ck = 0; ck < 4; ck++) {
      v[ck] = *(f16x8*)&Qa[t * 32 + ck * 8];
#pragma unroll
      for (int u = 0; u < 8; u++) { float f = (float)v[ck][u]; s = fmaf(f, f, s); }
    }
    float sc_ = rsqrtf(s) * rtau * LOG2E;
#pragma unroll
    for (int ck = 0; ck < 4; ck++) {
      f16x8 o;
#pragma unroll
      for (int u = 0; u < 8; u++) o[u] = (f16)((float)v[ck][u] * sc_);
      *(f16x8*)&Qa[t * 32 + ck * 8] = o;
    }
  } else {
    int t = tid - 256;
    float s = 0.f;
    f16x8 v[4];
#pragma unroll
    for (int ck = 0; ck < 4; ck++) {
      v[ck] = *(f16x8*)&Ka[t * 32 + ck * 8];
#pragma unroll
      for (int u = 0; u < 8; u++) { float f = (float)v[ck][u]; s = fmaf(f, f, s); }
    }
    float sc_ = rsqrtf(s);
#pragma unroll
    for (int ck = 0; ck < 4; ck++) {
      f16x8 o;
#pragma unroll
      for (int u = 0; u < 8; u++) o[u] = (f16)((float)v[ck][u] * sc_);
      *(f16x8*)&Ka[t * 32 + ck * 8] = o;
    }
  }
  __syncthreads();

  // hoist Q fragments; afterwards Qa region is dead -> reuse as per-wave P.
  f16x8 qf[2];
#pragma unroll
  for (int e = 0; e < 2; e++) qf[e] = ld8(Qa, wv * 32 + e * 16 + lm, lq);
  f16* Pme = (f16*)smem + wv * 1024;  // wave's own 32x32 slice (== its Q rows)

  f32x4 acco[2][2] = {};
  float lsum[2][4] = {};
  int loff[4];
#pragma unroll
  for (int r = 0; r < 4; r++) loff[r] = lq * 4 + r - lm + 15;
  int rowt = wv * 2;

  // ---- Phase 2: flash attention over 32-key chunks, no barriers
  for (int n0 = 0; n0 < Tt; n0 += 32) {
    f16x8 kf[2];
#pragma unroll
    for (int nt = 0; nt < 2; nt++) kf[nt] = ld8(Ka, n0 + nt * 16 + lm, lq);
    f32x4 zero = {0.f, 0.f, 0.f, 0.f};
    f32x4 sc[2][2];
#pragma unroll
    for (int e = 0; e < 2; e++)
#pragma unroll
      for (int nt = 0; nt < 2; nt++)
        sc[e][nt] = __builtin_amdgcn_mfma_f32_16x16x32_f16(qf[e], kf[nt], zero,
                                                           0, 0, 0);
#pragma unroll
    for (int e = 0; e < 2; e++) {
#pragma unroll
      for (int nt = 0; nt < 2; nt++) {
        int tboff = (rowt + e - (n0 >> 4) - nt + 15) << 5;
#pragma unroll
        for (int r = 0; r < 4; r++) {
          float p = exp2f(sc[e][nt][r] + tb2[tboff + loff[r]]);
          lsum[e][r] += p;
          Pme[sidx(e * 16 + lq * 4 + r, nt * 16 + lm)] = (f16)p;
        }
      }
    }
    asm volatile("s_waitcnt lgkmcnt(0)" ::: "memory");
    f16x8 pf[2], vf[2];
#pragma unroll
    for (int e = 0; e < 2; e++) pf[e] = ld8(Pme, e * 16 + lm, lq);
#pragma unroll
    for (int dt = 0; dt < 2; dt++)
      vf[dt] = vld8(Vt, dt * 16 + lm, (n0 >> 3) + lq);
#pragma unroll
    for (int e = 0; e < 2; e++)
#pragma unroll
      for (int dt = 0; dt < 2; dt++)
        acco[e][dt] = __builtin_amdgcn_mfma_f32_16x16x32_f16(pf[e], vf[dt],
                                                             acco[e][dt], 0, 0, 0);
  }

  // row-sum reduce across the 16 col-lanes, then normalize + store
#pragma unroll
  for (int e = 0; e < 2; e++)
#pragma unroll
    for (int r = 0; r < 4; r++) {
      float v = lsum[e][r];
      v += __shfl_xor(v, 1);
      v += __shfl_xor(v, 2);
      v += __shfl_xor(v, 4);
      v += __shfl_xor(v, 8);
      lsum[e][r] = __builtin_amdgcn_rcpf(v);
    }
#pragma unroll
  for (int e = 0; e < 2; e++)
#pragma unroll
    for (int dt = 0; dt < 2; dt++)
#pragma unroll
      for (int r = 0; r < 4; r++) {
        int t = wv * 32 + e * 16 + lq * 4 + r;
        int d = dt * 16 + lm;
        attnH[((size_t)b * Tt + t) * Cc + h * HD + d] =
            (f16)(acco[e][dt][r] * lsum[e][r]);
      }
}

// ---------------------------------------------------------------------------
// Kernel 3: MFMA proj GEMM.  A fp16 [B*T][256] x Wf fp16 [256][256]
// -> out[b][c][t].  mfma(W-frag(c), A-frag(t)) => C col = t, coalesced stores.
// ---------------------------------------------------------------------------
__global__ __launch_bounds__(256, 4) void proj_gemm(
    const f16* __restrict__ A, const f16* __restrict__ wf,
    const float* __restrict__ bp, float* __restrict__ out) {
  __shared__ __align__(16) f16 Xs[128 * 32];  // rows t
  __shared__ __align__(16) f16 Ws[128 * 32];  // rows c
  __shared__ float sB[128];
  int tid = threadIdx.x;
  int row0 = blockIdx.x * 128;  // global bt row
  int n0g = blockIdx.y * 128;   // global c col
  int b = row0 >> 8, t0 = row0 & 255;
  int wv = tid >> 6, ln = tid & 63, lq = ln >> 4, lm = ln & 15;
  int cw = (wv & 1) * 64, tw = (wv >> 1) * 64;

  if (tid < 128) sB[tid] = bp[n0g + tid];

  f32x4 acc[4][4] = {};
  for (int k0 = 0; k0 < Cc; k0 += 32) {
#pragma unroll
    for (int it = 0; it < 2; it++) {
      int idx = it * 256 + tid;
      int t = idx >> 2, ck = idx & 3;
      f16x8 v = *(const f16x8*)&A[(size_t)(row0 + t) * Cc + k0 + ck * 8];
      st8(Xs, t, ck, v);
    }
#pragma unroll
    for (int it = 0; it < 2; it++) {
      int idx = it * 256 + tid;
      int n = idx >> 2, ck = idx & 3;
      f16x8 v = *(const f16x8*)&wf[(size_t)(n0g + n) * Cc + k0 + ck * 8];
      st8(Ws, n, ck, v);
    }
    __syncthreads();
    f16x8 wfr[4], af[4];
#pragma unroll
    for (int i = 0; i < 4; i++) wfr[i] = ld8(Ws, cw + i * 16 + lm, lq);
#pragma unroll
    for (int j = 0; j < 4; j++) af[j] = ld8(Xs, tw + j * 16 + lm, lq);
#pragma unroll
    for (int i = 0; i < 4; i++)
#pragma unroll
      for (int j = 0; j < 4; j++)
        acc[i][j] = __builtin_amdgcn_mfma_f32_16x16x32_f16(wfr[i], af[j],
                                                           acc[i][j], 0, 0, 0);
    __syncthreads();
  }

  // epilogue: C row = c-local, col = t-local; stores contiguous in t
#pragma unroll
  for (int i = 0; i < 4; i++)
#pragma unroll
    for (int r = 0; r < 4; r++) {
      int crl = cw + i * 16 + lq * 4 + r;
      float bias = sB[crl];
#pragma unroll
      for (int j = 0; j < 4; j++) {
        int tcl = tw + j * 16 + lm;
        out[(size_t)b * 65536 + (size_t)(n0g + crl) * 256 + t0 + tcl] =
            acc[i][j][r] + bias;
      }
    }
}

// ---------------------------------------------------------------------------
extern "C" void kernel_launch(void* const* d_in, const int* in_sizes, int n_in,
                              void* d_out, int out_size, void* d_ws,
                              size_t ws_size, hipStream_t stream) {
  const float* x = (const float*)d_in[0];
  const float* w_qkv = (const float*)d_in[1];
  const float* b_qkv = (const float*)d_in[2];
  const float* w_proj = (const float*)d_in[3];
  const float* b_proj = (const float*)d_in[4];
  const float* mw1 = (const float*)d_in[5];
  const float* mb1 = (const float*)d_in[6];
  const float* mw2 = (const float*)d_in[7];
  const float* mb2 = (const float*)d_in[8];
  const float* tau = (const float*)d_in[9];
  float* out = (float*)d_out;

  // ws: table (7688 f) | tablemax (8 f) | wpf (65536 f16) | attnH (33.5 MB)
  const size_t NEEDED = (size_t)(TBL * NH + NH) * 4 + (size_t)65536 * 2 +
                        (size_t)256 * NH * Tt * HD * 2;
  if (ws_size < NEEDED) return;

  float* table = (float*)d_ws;
  float* tablemax = table + TBL * NH;
  f16* wpf = (f16*)(tablemax + NH);
  f16* attnH = wpf + 65536;

  prep_kernel<<<40, 256, 0, stream>>>(mw1, mb1, mw2, mb2, w_proj, table,
                                      tablemax, wpf);
  fused_attn<<<256 * NH, 512, 0, stream>>>(x, w_qkv, b_qkv, table, tablemax,
                                           tau, attnH);
  dim3 g3(512, 2);
  proj_gemm<<<g3, 256, 0, stream>>>(attnH, wpf, b_proj, out);
}

// Round 6
// 278.940 us; speedup vs baseline: 1.5253x; 1.5253x over previous
//
#include <hip/hip_runtime.h>
#include <math.h>

#define Cc 256
#define NH 8
#define HD 32
#define Tt 256
#define MH 256
#define TBL 961  // 31*31 distinct relative offsets

typedef _Float16 f16;
typedef f16 f16x4 __attribute__((ext_vector_type(4)));
typedef f16 f16x8 __attribute__((ext_vector_type(8)));
typedef float f32x4 __attribute__((ext_vector_type(4)));

// stride-32 f16 rows, 16B-chunk XOR swizzle, key=(row>>2)&3.
__device__ __forceinline__ f16x8 ld8(const f16* base, int row, int kc) {
  return *(const f16x8*)&base[row * 32 + ((kc ^ ((row >> 2) & 3)) << 3)];
}
__device__ __forceinline__ void st8(f16* base, int row, int kc, f16x8 v) {
  *(f16x8*)&base[row * 32 + ((kc ^ ((row >> 2) & 3)) << 3)] = v;
}
__device__ __forceinline__ int sidx(int row, int col) {
  return row * 32 + (((col >> 3) ^ ((row >> 2) & 3)) << 3) + (col & 7);
}
// Vt: [d=32][t=256] stride 256, full 3-bit XOR: chunk ^= (d&7).
__device__ __forceinline__ int vsidx(int d, int t) {
  return d * 256 + (((t >> 3) ^ (d & 7)) << 3) + (t & 7);
}
__device__ __forceinline__ f16x8 vld8(const f16* base, int d, int tch) {
  return *(const f16x8*)&base[d * 256 + ((tch ^ (d & 7)) << 3)];
}

// ---------------------------------------------------------------------------
// Kernel 1: prep.  Blocks 0..7: bias-MLP table for one head each.
// Blocks 8..39: convert w_proj fp32 -> fp16.
// ---------------------------------------------------------------------------
__global__ __launch_bounds__(256) void prep_kernel(
    const float* __restrict__ mw1, const float* __restrict__ mb1,
    const float* __restrict__ mw2, const float* __restrict__ mb2,
    const float* __restrict__ w_proj, float* __restrict__ table,
    float* __restrict__ tablemax, f16* __restrict__ wpf) {
  int blk = blockIdx.x, tid = threadIdx.x;
  if (blk >= NH) {
    int base = (blk - NH) * 2048 + tid * 8;
    f16x8 v;
#pragma unroll
    for (int u = 0; u < 8; u++) v[u] = (f16)w_proj[base + u];
    *(f16x8*)&wpf[base] = v;
    return;
  }
  __shared__ float s_w1a[MH], s_w1b[MH], s_b1[MH], s_w2[MH];
  __shared__ float red[256];
  for (int i = tid; i < MH; i += 256) {
    s_w1a[i] = mw1[2 * i];
    s_w1b[i] = mw1[2 * i + 1];
    s_b1[i] = mb1[i];
    s_w2[i] = mw2[blk * MH + i];
  }
  __syncthreads();
  float lmax = -1e30f;
  float b2 = mb2[blk];
  for (int idx = tid; idx < TBL; idx += 256) {
    float fdi = (float)(idx / 31 - 15);
    float fdj = (float)(idx % 31 - 15);
    float d0 = (fdi > 0.f ? 1.f : (fdi < 0.f ? -1.f : 0.f)) * log1pf(fabsf(fdi));
    float d1 = (fdj > 0.f ? 1.f : (fdj < 0.f ? -1.f : 0.f)) * log1pf(fabsf(fdj));
    float o = b2;
    for (int m = 0; m < MH; m++) {
      float hid = fmaxf(fmaf(d0, s_w1a[m], fmaf(d1, s_w1b[m], s_b1[m])), 0.f);
      o = fmaf(hid, s_w2[m], o);
    }
    table[blk * TBL + idx] = o;
    lmax = fmaxf(lmax, o);
  }
  red[tid] = lmax;
  __syncthreads();
  for (int s = 128; s > 0; s >>= 1) {
    if (tid < s) red[tid] = fmaxf(red[tid], red[tid + s]);
    __syncthreads();
  }
  if (tid == 0) tablemax[blk] = red[0];
}

// ---------------------------------------------------------------------------
// Kernel 2: fused QKV + cosine-sim attention, swapped-operand phase 2.
// Block = (b,h), 512 thr = 8 waves.  LDS 68352 B -> 2 blocks/CU.
// R5 lesson: do NOT set launch_bounds min-waves above what the accumulator
// footprint allows (spill -> 3x HBM traffic).  (512,4): 128-reg budget.
// ---------------------------------------------------------------------------
__global__ __launch_bounds__(512, 4) void fused_attn(
    const float* __restrict__ x, const float* __restrict__ w_qkv,
    const float* __restrict__ b_qkv, const float* __restrict__ table,
    const float* __restrict__ tablemax, const float* __restrict__ tau,
    f16* __restrict__ attnH) {
  __shared__ __align__(16) char smem[68352];
  f16* Qa = (f16*)smem;                    // 16384 B  (ph1: Xa; ph2: P w0..6)
  f16* Ka = (f16*)(smem + 16384);          // 16384 B  (ph1: Wa in first 6 KB)
  f16* Vt = (f16*)(smem + 32768);          // 16384 B
  f16* Pspare = (f16*)(smem + 49152);      // 2304 B   (wave 7's P)
  float* tbv = (float*)(smem + 51456);     // 31x32 float4 = 15872 B
  float* rs = (float*)(smem + 67328);      // 8x32 f32 = 1024 B
  f16* Xa = (f16*)smem;
  f16* Wa = (f16*)(smem + 16384);

  int tid = threadIdx.x;
  int bh = blockIdx.x, b = bh >> 3, h = bh & 7;
  int wv = tid >> 6, ln = tid & 63, lq = ln >> 4, lm = ln & 15;

  const float LOG2E = 1.4426950408889634f;
  float rtau = 1.0f / fmaxf(tau[h], 0.01f);
  float tmaxh = tablemax[h];

  // tbv[di][c] = float4{ tb(c), tb(c-1), tb(c-2), tb(c-3) }, log2-domain,
  // pre-shifted.  Lane reads component r at dj = c0l - r.
  for (int idx = tid; idx < 31 * 32; idx += 512) {
    int di_ = idx >> 5, c = idx & 31;
    float4 v;
    float* vp = (float*)&v;
#pragma unroll
    for (int u = 0; u < 4; u++) {
      int dj = c - u;
      dj = dj < 0 ? 0 : (dj > 30 ? 30 : dj);
      vp[u] = (table[h * TBL + di_ * 31 + dj] - tmaxh - rtau * 1.0001f) * LOG2E;
    }
    *(float4*)&tbv[idx * 4] = v;
  }

  float bj[6];
#pragma unroll
  for (int nt = 0; nt < 6; nt++) {
    int n = nt * 16 + lm;
    int row = ((n >> 5) << 8) + (h << 5) + (n & 31);
    bj[nt] = b_qkv[row];
  }

  // ---- Phase 1: QKV GEMM, M=256 N=96 K=256, MFMA 16x16x32_f16
  f32x4 acc[2][6] = {};
  for (int c0 = 0; c0 < Cc; c0 += 32) {
    {
      int t = tid & 255, cg = tid >> 8;
      f16x8 v0, v1;
#pragma unroll
      for (int cc = 0; cc < 8; cc++)
        v0[cc] = (f16)x[(size_t)b * 65536 + (size_t)(c0 + cg * 16 + cc) * 256 + t];
#pragma unroll
      for (int cc = 0; cc < 8; cc++)
        v1[cc] = (f16)x[(size_t)b * 65536 + (size_t)(c0 + cg * 16 + 8 + cc) * 256 + t];
      st8(Xa, t, cg * 2 + 0, v0);
      st8(Xa, t, cg * 2 + 1, v1);
    }
    if (tid < 384) {
      int n = tid >> 2, ck = tid & 3;
      int row = ((n >> 5) << 8) + (h << 5) + (n & 31);
      const float* wp = w_qkv + (size_t)row * Cc + c0 + ck * 8;
      f16x8 v;
#pragma unroll
      for (int u = 0; u < 8; u++) v[u] = (f16)wp[u];
      st8(Wa, n, ck, v);
    }
    __syncthreads();
    f16x8 af[2], bf[6];
#pragma unroll
    for (int e = 0; e < 2; e++) af[e] = ld8(Xa, wv * 32 + e * 16 + lm, lq);
#pragma unroll
    for (int nt = 0; nt < 6; nt++) bf[nt] = ld8(Wa, nt * 16 + lm, lq);
#pragma unroll
    for (int e = 0; e < 2; e++)
#pragma unroll
      for (int nt = 0; nt < 6; nt++)
        acc[e][nt] = __builtin_amdgcn_mfma_f32_16x16x32_f16(af[e], bf[nt],
                                                            acc[e][nt], 0, 0, 0);
    __syncthreads();
  }

  // epilogue: + bias, scatter to Qa/Ka (t-major) and Vt (d-major)
#pragma unroll
  for (int e = 0; e < 2; e++) {
#pragma unroll
    for (int nt = 0; nt < 6; nt++) {
      int d = (nt & 1) * 16 + lm;
#pragma unroll
      for (int r = 0; r < 4; r++) {
        int t = wv * 32 + e * 16 + lq * 4 + r;
        f16 v = (f16)(acc[e][nt][r] + bj[nt]);
        if (nt < 2)      Qa[sidx(t, d)] = v;
        else if (nt < 4) Ka[sidx(t, d)] = v;
        else             Vt[vsidx(d, t)] = v;
      }
    }
  }
  __syncthreads();

  // normalize Q,K rows in place (fold rtau*log2e into Q)
  if (tid < 256) {
    int t = tid;
    float s = 0.f;
    f16x8 v[4];
#pragma unroll
    for (int ck = 0; ck < 4; ck++) {
      v[ck] = *(f16x8*)&Qa[t * 32 + ck * 8];
#pragma unroll
      for (int u = 0; u < 8; u++) { float f = (float)v[ck][u]; s = fmaf(f, f, s); }
    }
    float sc_ = rsqrtf(s) * rtau * LOG2E;
#pragma unroll
    for (int ck = 0; ck < 4; ck++) {
      f16x8 o;
#pragma unroll
      for (int u = 0; u < 8; u++) o[u] = (f16)((float)v[ck][u] * sc_);
      *(f16x8*)&Qa[t * 32 + ck * 8] = o;
    }
  } else {
    int t = tid - 256;
    float s = 0.f;
    f16x8 v[4];
#pragma unroll
    for (int ck = 0; ck < 4; ck++) {
      v[ck] = *(f16x8*)&Ka[t * 32 + ck * 8];
#pragma unroll
      for (int u = 0; u < 8; u++) { float f = (float)v[ck][u]; s = fmaf(f, f, s); }
    }
    float sc_ = rsqrtf(s);
#pragma unroll
    for (int ck = 0; ck < 4; ck++) {
      f16x8 o;
#pragma unroll
      for (int u = 0; u < 8; u++) o[u] = (f16)((float)v[ck][u] * sc_);
      *(f16x8*)&Ka[t * 32 + ck * 8] = o;
    }
  }
  __syncthreads();

  // hoist Q fragments (B-operand rows q = wv*32+e*16+lm), then Qa -> P space
  f16x8 qf[2];
#pragma unroll
  for (int e = 0; e < 2; e++) qf[e] = ld8(Qa, wv * 32 + e * 16 + lm, lq);
  __syncthreads();  // all waves done reading Qa before it becomes P

  f16* Pme = (wv < 7) ? (Qa + wv * 1152) : Pspare;  // 32 rows x stride 36 f16
  int c0l = lm - lq * 4 + 15;                        // lane-constant dj base
  const float4* tbp = (const float4*)tbv;
  float lsum[2] = {0.f, 0.f};
  f32x4 acco[2][2] = {};
  int dibase = wv * 2 + 15;

  // ---- Phase 2: S^T = mfma(K,Q) -> packed b64 P writes -> PV. No barriers.
  for (int n0 = 0; n0 < Tt; n0 += 32) {
    f16x8 kf[2];
#pragma unroll
    for (int nt = 0; nt < 2; nt++) kf[nt] = ld8(Ka, n0 + nt * 16 + lm, lq);
    f32x4 zero = {0.f, 0.f, 0.f, 0.f};
    f32x4 sc[2][2];
#pragma unroll
    for (int e = 0; e < 2; e++)
#pragma unroll
      for (int nt = 0; nt < 2; nt++)
        sc[e][nt] = __builtin_amdgcn_mfma_f32_16x16x32_f16(kf[nt], qf[e], zero,
                                                           0, 0, 0);
#pragma unroll
    for (int e = 0; e < 2; e++) {
#pragma unroll
      for (int nt = 0; nt < 2; nt++) {
        int di_ = dibase + e - (n0 >> 4) - nt;
        float4 bv = tbp[di_ * 32 + c0l];
        const float* bvp = (const float*)&bv;
        f16x4 pv;
#pragma unroll
        for (int r = 0; r < 4; r++) {
          float p = exp2f(sc[e][nt][r] + bvp[r]);
          lsum[e] += p;
          pv[r] = (f16)p;
        }
        *(f16x4*)&Pme[(e * 16 + lm) * 36 + nt * 16 + lq * 4] = pv;
      }
    }
    asm volatile("s_waitcnt lgkmcnt(0)" ::: "memory");
    f16x8 pf[2], vf[2];
#pragma unroll
    for (int e = 0; e < 2; e++) {
      f16x4 p0 = *(f16x4*)&Pme[(e * 16 + lm) * 36 + lq * 8];
      f16x4 p1 = *(f16x4*)&Pme[(e * 16 + lm) * 36 + lq * 8 + 4];
      pf[e] = __builtin_shufflevector(p0, p1, 0, 1, 2, 3, 4, 5, 6, 7);
    }
#pragma unroll
    for (int dt = 0; dt < 2; dt++)
      vf[dt] = vld8(Vt, dt * 16 + lm, (n0 >> 3) + lq);
#pragma unroll
    for (int e = 0; e < 2; e++)
#pragma unroll
      for (int dt = 0; dt < 2; dt++)
        acco[e][dt] = __builtin_amdgcn_mfma_f32_16x16x32_f16(pf[e], vf[dt],
                                                             acco[e][dt], 0, 0, 0);
  }

  // lsum lives at lane lm per (e); reduce over lq lanes, redistribute via LDS
#pragma unroll
  for (int e = 0; e < 2; e++) {
    float v = lsum[e];
    v += __shfl_xor(v, 16);
    v += __shfl_xor(v, 32);
    lsum[e] = v;
  }
  if (ln < 16) {
    rs[wv * 32 + lm] = lsum[0];
    rs[wv * 32 + 16 + lm] = lsum[1];
  }
  asm volatile("s_waitcnt lgkmcnt(0)" ::: "memory");
#pragma unroll
  for (int e = 0; e < 2; e++)
#pragma unroll
    for (int r = 0; r < 4; r++) {
      float rl = __builtin_amdgcn_rcpf(rs[wv * 32 + e * 16 + lq * 4 + r]);
      int q = wv * 32 + e * 16 + lq * 4 + r;
#pragma unroll
      for (int dt = 0; dt < 2; dt++) {
        int d = dt * 16 + lm;
        attnH[((size_t)b * Tt + q) * Cc + h * HD + d] =
            (f16)(acco[e][dt][r] * rl);
      }
    }
}

// ---------------------------------------------------------------------------
// Kernel 3: MFMA proj GEMM, coalesced staging.  A fp16 [B*T][256] x Wf fp16
// [256][256] -> out[b][c][t].  K-step 64 (128B row segments), stride-72 LDS,
// 37.4 KB -> 4 blocks/CU.
// ---------------------------------------------------------------------------
__global__ __launch_bounds__(256, 4) void proj_gemm(
    const f16* __restrict__ A, const f16* __restrict__ wf,
    const float* __restrict__ bp, float* __restrict__ out) {
  __shared__ __align__(16) f16 Af[128 * 72];   // 18432 B
  __shared__ __align__(16) f16 Wsh[128 * 72];  // 18432 B
  __shared__ float sB[128];
  int tid = threadIdx.x;
  int row0 = blockIdx.x * 128;
  int n0g = blockIdx.y * 128;
  int b = row0 >> 8, t0 = row0 & 255;
  int wv = tid >> 6, ln = tid & 63, lq = ln >> 4, lm = ln & 15;
  int cw = (wv & 1) * 64, tw = (wv >> 1) * 64;

  if (tid < 128) sB[tid] = bp[n0g + tid];

  f32x4 acc[4][4] = {};
  for (int k0 = 0; k0 < Cc; k0 += 64) {
#pragma unroll
    for (int p = 0; p < 4; p++) {
      int idx = p * 256 + tid;
      int row = idx >> 3, ch = idx & 7;
      f16x8 v = *(const f16x8*)&A[(size_t)(row0 + row) * Cc + k0 + ch * 8];
      *(f16x8*)&Af[row * 72 + ch * 8] = v;
    }
#pragma unroll
    for (int p = 0; p < 4; p++) {
      int idx = p * 256 + tid;
      int row = idx >> 3, ch = idx & 7;
      f16x8 v = *(const f16x8*)&wf[(size_t)(n0g + row) * Cc + k0 + ch * 8];
      *(f16x8*)&Wsh[row * 72 + ch * 8] = v;
    }
    __syncthreads();
#pragma unroll
    for (int kk = 0; kk < 2; kk++) {
      f16x8 wfr[4], af[4];
#pragma unroll
      for (int i = 0; i < 4; i++)
        wfr[i] = *(f16x8*)&Wsh[(cw + i * 16 + lm) * 72 + (kk * 4 + lq) * 8];
#pragma unroll
      for (int j = 0; j < 4; j++)
        af[j] = *(f16x8*)&Af[(tw + j * 16 + lm) * 72 + (kk * 4 + lq) * 8];
#pragma unroll
      for (int i = 0; i < 4; i++)
#pragma unroll
        for (int j = 0; j < 4; j++)
          acc[i][j] = __builtin_amdgcn_mfma_f32_16x16x32_f16(wfr[i], af[j],
                                                             acc[i][j], 0, 0, 0);
    }
    __syncthreads();
  }

  // epilogue: D[c][t], col = t -> coalesced stores
#pragma unroll
  for (int i = 0; i < 4; i++)
#pragma unroll
    for (int r = 0; r < 4; r++) {
      int crl = cw + i * 16 + lq * 4 + r;
      float bias = sB[crl];
#pragma unroll
      for (int j = 0; j < 4; j++) {
        int tcl = tw + j * 16 + lm;
        out[(size_t)b * 65536 + (size_t)(n0g + crl) * 256 + t0 + tcl] =
            acc[i][j][r] + bias;
      }
    }
}

// ---------------------------------------------------------------------------
extern "C" void kernel_launch(void* const* d_in, const int* in_sizes, int n_in,
                              void* d_out, int out_size, void* d_ws,
                              size_t ws_size, hipStream_t stream) {
  const float* x = (const float*)d_in[0];
  const float* w_qkv = (const float*)d_in[1];
  const float* b_qkv = (const float*)d_in[2];
  const float* w_proj = (const float*)d_in[3];
  const float* b_proj = (const float*)d_in[4];
  const float* mw1 = (const float*)d_in[5];
  const float* mb1 = (const float*)d_in[6];
  const float* mw2 = (const float*)d_in[7];
  const float* mb2 = (const float*)d_in[8];
  const float* tau = (const float*)d_in[9];
  float* out = (float*)d_out;

  const size_t NEEDED = (size_t)(TBL * NH + NH) * 4 + (size_t)65536 * 2 +
                        (size_t)256 * NH * Tt * HD * 2;
  if (ws_size < NEEDED) return;

  float* table = (float*)d_ws;
  float* tablemax = table + TBL * NH;
  f16* wpf = (f16*)(tablemax + NH);
  f16* attnH = wpf + 65536;

  prep_kernel<<<40, 256, 0, stream>>>(mw1, mb1, mw2, mb2, w_proj, table,
                                      tablemax, wpf);
  fused_attn<<<256 * NH, 512, 0, stream>>>(x, w_qkv, b_qkv, table, tablemax,
                                           tau, attnH);
  dim3 g3(512, 2);
  proj_gemm<<<g3, 256, 0, stream>>>(attnH, wpf, b_proj, out);
}